// Round 9
// baseline (431.934 us; speedup 1.0000x reference)
//
#include <hip/hip_runtime.h>
#include <cmath>

#define NPTS 4096
#define NPOINT 204   // int(4096 * 0.05)
#define NPCT 5
#define MAXNS 409    // int(4096 * 0.10)
#define NGROUP 408   // B * NPOINT
#define NPART (NGROUP * NPCT)
#define FLAG_TAG 0x5A5A1000u
#define SPIN_LIMIT (1 << 21)   // fail-safe: wrong answer instead of hang

typedef unsigned long long u64;
typedef float f32x2 __attribute__((ext_vector_type(2)));

struct LossParams {
    int   nsample[NPCT];
    float r2[NPCT];
    float wscale[NPCT];   // (p*100)^2 / (B*NPOINT*NPCT)
    float expect_len;
};

// ---------------- DPP wave64 reductions ------------------------------------
template <int CTRL>
__device__ __forceinline__ int dpp_imax(int v) {
    int t = __builtin_amdgcn_update_dpp(0, v, CTRL, 0xf, 0xf, true);
    return v > t ? v : t;
}
template <int CTRL>
__device__ __forceinline__ int dpp_imin(int v) {
    int t = __builtin_amdgcn_update_dpp(0x7fffffff, v, CTRL, 0xf, 0xf, false);
    return v < t ? v : t;
}
__device__ __forceinline__ int wave_max_i(int v) {
    v = dpp_imax<0x111>(v); v = dpp_imax<0x112>(v);
    v = dpp_imax<0x114>(v); v = dpp_imax<0x118>(v);
    v = dpp_imax<0x142>(v); v = dpp_imax<0x143>(v);
    return __builtin_amdgcn_readlane(v, 63);
}
__device__ __forceinline__ int wave_min_i(int v) {
    v = dpp_imin<0x111>(v); v = dpp_imin<0x112>(v);
    v = dpp_imin<0x114>(v); v = dpp_imin<0x118>(v);
    v = dpp_imin<0x142>(v); v = dpp_imin<0x143>(v);
    return __builtin_amdgcn_readlane(v, 63);
}
template <int CTRL>
__device__ __forceinline__ u64 dpp_u64max(u64 v) {
    int lo = (int)(unsigned)v;
    int hi = (int)(unsigned)(v >> 32);
    unsigned slo = (unsigned)__builtin_amdgcn_update_dpp(0, lo, CTRL, 0xf, 0xf, true);
    unsigned shi = (unsigned)__builtin_amdgcn_update_dpp(0, hi, CTRL, 0xf, 0xf, true);
    u64 o = ((u64)shi << 32) | slo;
    return v > o ? v : o;
}

// ---------------------------------------------------------------------------
// Fused kernel. Blocks 0,1: FPS for batch b=blockIdx.x, publishing each
// selected index as a tagged flag (device-scope atomic store). Blocks 2..:
// one (group, pct) each; spin on the group's flag, then the PROVEN R5 group
// math (ballot compaction + med3 min2, absmax .0156).
// fps now tracks winner COORDS through the argmax (no 64 KB pts[] array) so
// the merged kernel's LDS stays ~7 KB -> high residency for group blocks.
// ---------------------------------------------------------------------------
__global__ __launch_bounds__(256) void fused_kernel(const float* __restrict__ pcd,
                                                    unsigned* __restrict__ flags,
                                                    float* __restrict__ partials,
                                                    LossParams P) {
    const int t    = threadIdx.x;
    const int wave = t >> 6, lane = t & 63;

    __shared__ u64    skeys[2][4];
    __shared__ float4 scoord[2][4];
    __shared__ float4 gpts[MAXNS + 8];
    __shared__ int    s_wtot[4];
    __shared__ float  s_part[4];
    __shared__ int    s_qi;

    if (blockIdx.x < 2) {
        // ================= FPS part =================
#pragma clang fp contract(off)
        const int b = blockIdx.x;
        const float* base = pcd + (size_t)b * NPTS * 3;
        unsigned* fl = flags + b * NPOINT;

        f32x2 X[8], Y[8], Z[8], D[8];
        #pragma unroll
        for (int q = 0; q < 8; ++q) {
            int n0 = (2 * q) * 256 + t;
            int n1 = (2 * q + 1) * 256 + t;
            X[q] = (f32x2){base[3 * n0 + 0], base[3 * n1 + 0]};
            Y[q] = (f32x2){base[3 * n0 + 1], base[3 * n1 + 1]};
            Z[q] = (f32x2){base[3 * n0 + 2], base[3 * n1 + 2]};
            D[q] = (f32x2){1e10f, 1e10f};
        }
        if (t == 0)
            __hip_atomic_store(&fl[0], FLAG_TAG | 0u,
                               __ATOMIC_RELEASE, __HIP_MEMORY_SCOPE_AGENT);
        float cx = base[0], cy = base[1], cz = base[2];   // point 0

        for (int it = 1; it < NPOINT; ++it) {
            f32x2 cxx = (f32x2){cx, cx};
            f32x2 cyy = (f32x2){cy, cy};
            f32x2 czz = (f32x2){cz, cz};
            int bb = -1, bi = 0;
            float bx = 0.0f, by = 0.0f, bz = 0.0f;
            #pragma unroll
            for (int q = 0; q < 8; ++q) {
                f32x2 dx = X[q] - cxx, dy = Y[q] - cyy, dz = Z[q] - czz;
                f32x2 d  = (dx * dx + dy * dy) + dz * dz;
                f32x2 dd = D[q];
                float d0 = fminf(dd.x, d.x);
                float d1 = fminf(dd.y, d.y);
                D[q] = (f32x2){d0, d1};
                int b0 = __float_as_int(d0);   // nonneg: int cmp == float cmp
                int b1 = __float_as_int(d1);
                if (b0 > bb) { bb = b0; bi = (2 * q) * 256 + t;
                               bx = X[q].x; by = Y[q].x; bz = Z[q].x; }
                if (b1 > bb) { bb = b1; bi = (2 * q + 1) * 256 + t;
                               bx = X[q].y; by = Y[q].y; bz = Z[q].y; }
            }
            int wmax = wave_max_i(bb);
            int cand = (bb == wmax) ? bi : 0x7fffffff;
            int widx = wave_min_i(cand);       // smallest index among ties
            if (bb == wmax && bi == widx)      // exactly one thread per wave
                scoord[it & 1][wave] = make_float4(bx, by, bz, 0.0f);
            if (lane == 0)
                skeys[it & 1][wave] =
                    ((u64)(unsigned)wmax << 32) | (unsigned)~(unsigned)widx;
            __syncthreads();
            u64 kv = skeys[it & 1][lane & 3];
            kv = dpp_u64max<0x111>(kv);
            kv = dpp_u64max<0x112>(kv);
            unsigned lo3 = (unsigned)__builtin_amdgcn_readlane((int)(unsigned)kv, 3);
            int last = (int)~lo3;
            float4 wc = scoord[it & 1][(last & 255) >> 6];  // winner wave's coords
            cx = wc.x; cy = wc.y; cz = wc.z;
            if (t == 0)
                __hip_atomic_store(&fl[it], FLAG_TAG | (unsigned)last,
                                   __ATOMIC_RELEASE, __HIP_MEMORY_SCOPE_AGENT);
        }
        return;
    }

    // ================= GROUP part (R5 math, verbatim) =================
    const int xid  = blockIdx.x - 2;       // 0 .. NPART-1
    const int pidx = xid % NPCT;
    const int gg   = xid / NPCT;           // 0 .. NGROUP-1
    const int b    = gg & 1;               // alternate batches: backfill matches
    const int m    = gg >> 1;              // fps emission order
    const int   ns = P.nsample[pidx];
    const float r2 = P.r2[pidx];
    const float* base = pcd + (size_t)b * NPTS * 3;

    if (t == 0) {
        unsigned v; int spins = 0;
        for (;;) {
            v = __hip_atomic_load(&flags[b * NPOINT + m],
                                  __ATOMIC_ACQUIRE, __HIP_MEMORY_SCOPE_AGENT);
            if ((v & 0xFFFFF000u) == FLAG_TAG) break;
            if (++spins > SPIN_LIMIT) { v = FLAG_TAG; break; }   // no-hang fail-safe
            __builtin_amdgcn_s_sleep(4);
        }
        s_qi = (int)(v & 0xFFFu);
    }
    __syncthreads();
    const int qi = s_qi;
    const float qx = base[3 * qi + 0], qy = base[3 * qi + 1], qz = base[3 * qi + 2];

    // ---- Phase A pass 1: ballot the wave's 16 sub-chunks of 64 points ----
    unsigned long long msk[16];
    int lbase[16];
    int run = 0;
    #pragma unroll 4
    for (int s = 0; s < 16; ++s) {
        int n = wave * 1024 + s * 64 + lane;
        float x = base[3 * n + 0];
        float y = base[3 * n + 1];
        float z = base[3 * n + 2];
        float d2;
        {
#pragma clang fp contract(off)
            float dx = qx - x, dy = qy - y, dz = qz - z;
            float aa = dx * dx, bb = dy * dy, cc = dz * dz;
            d2 = (aa + bb) + cc;
        }
        msk[s] = __ballot(d2 < r2);        // strict <, matches reference
        lbase[s] = run;
        run += __popcll(msk[s]);
    }
    if (lane == 0) s_wtot[wave] = run;
    __syncthreads();
    int w0 = s_wtot[0], w1 = s_wtot[1], w2 = s_wtot[2], w3 = s_wtot[3];
    int Bw = (wave > 0 ? w0 : 0) + (wave > 1 ? w1 : 0) + (wave > 2 ? w2 : 0);
    int cnt  = w0 + w1 + w2 + w3;
    int cntB = cnt < ns ? cnt : ns;        // real points kept
    const int npad = ns - cntB;

    // ---- Phase A pass 2: ordered compaction into LDS, w = |p|^2 ----
    #pragma unroll 4
    for (int s = 0; s < 16; ++s) {
        int gb = Bw + lbase[s];            // wave-uniform
        if (gb >= ns) break;
        unsigned long long mk = msk[s];
        bool in = (mk >> lane) & 1ull;
        int pos = gb + __popcll(mk & ((1ull << lane) - 1ull));
        if (in && pos < ns) {
            int n = wave * 1024 + s * 64 + lane;
            float x = base[3 * n], y = base[3 * n + 1], z = base[3 * n + 2];
            float sq = fmaf(x, x, fmaf(y, y, z * z));
            gpts[pos] = make_float4(x, y, z, sq);
        }
    }
    if (t < 8) gpts[cntB + t] = make_float4(1e6f, 1e6f, 1e6f, 3e12f);  // sentinels
    __syncthreads();

    // ---- Phase B: 2nd-smallest h (incl. self) via med3; d2 = sq_i + m2 ----
    float sum = 0.0f;
    if (cntB > 256) {
        const int i0 = t, i1 = t + 256;
        const bool a1 = i1 < cntB;
        float4 p0 = gpts[i0];
        float4 p1 = gpts[a1 ? i1 : 0];
        float m10 = 1e30f, m20 = 1e30f;
        float m11 = 1e30f, m21 = 1e30f;
        for (int jt = 0; jt < cntB; jt += 8) {
            #pragma unroll
            for (int u = 0; u < 8; ++u) {
                float4 a = gpts[jt + u];
                float tt, h;
                tt = p0.x * a.x; tt = fmaf(p0.y, a.y, tt); tt = fmaf(p0.z, a.z, tt);
                h = fmaf(-2.0f, tt, a.w);
                m20 = __builtin_amdgcn_fmed3f(m10, m20, h);
                m10 = fminf(m10, h);
                tt = p1.x * a.x; tt = fmaf(p1.y, a.y, tt); tt = fmaf(p1.z, a.z, tt);
                h = fmaf(-2.0f, tt, a.w);
                m21 = __builtin_amdgcn_fmed3f(m11, m21, h);
                m11 = fminf(m11, h);
            }
        }
        float d0 = fmaxf(p0.w + m20, 0.0f);
        float d1 = fmaxf(p1.w + m21, 0.0f);
        if (!(i0 == 0 && npad > 0)) sum += sqrtf(d0);
        if (a1) sum += sqrtf(d1);
    } else {
        for (int i = t; i < cntB; i += 256) {
            float4 pi = gpts[i];
            float m1 = 1e30f, m2 = 1e30f;
            for (int jt = 0; jt < cntB; jt += 8) {
                #pragma unroll
                for (int u = 0; u < 8; ++u) {
                    float4 a = gpts[jt + u];
                    float tt, h;
                    tt = pi.x * a.x; tt = fmaf(pi.y, a.y, tt); tt = fmaf(pi.z, a.z, tt);
                    h = fmaf(-2.0f, tt, a.w);
                    m2 = __builtin_amdgcn_fmed3f(m1, m2, h);
                    m1 = fminf(m1, h);
                }
            }
            float dmin = fmaxf(pi.w + m2, 0.0f);
            if (!(i == 0 && npad > 0)) sum += sqrtf(dmin);
        }
    }
    #pragma unroll
    for (int off = 32; off; off >>= 1) sum += __shfl_down(sum, off);
    if (lane == 0) s_part[wave] = sum;
    __syncthreads();
    if (t == 0) {
        float tot = s_part[0] + s_part[1] + s_part[2] + s_part[3] + 0.1f * (float)ns;
        float u  = tot / (float)ns;
        float du = u - P.expect_len;
        partials[xid] = du * du / (P.expect_len + 0.1f) * P.wscale[pidx];
    }
}

// ---------------------------------------------------------------------------
// Reduce: sum the 2040 per-block partials -> d_out (no atomics anywhere).
// ---------------------------------------------------------------------------
__global__ __launch_bounds__(256) void reduce_kernel(const float* __restrict__ partials,
                                                     float* __restrict__ out) {
    const int t = threadIdx.x;
    __shared__ float sp[4];
    float s = 0.0f;
    for (int i = t; i < NPART; i += 256) s += partials[i];
    #pragma unroll
    for (int off = 32; off; off >>= 1) s += __shfl_down(s, off);
    if ((t & 63) == 0) sp[t >> 6] = s;
    __syncthreads();
    if (t == 0) out[0] = sp[0] + sp[1] + sp[2] + sp[3];
}

extern "C" void kernel_launch(void* const* d_in, const int* in_sizes, int n_in,
                              void* d_out, int out_size, void* d_ws, size_t ws_size,
                              hipStream_t stream) {
    const float* pcd = (const float*)d_in[0];
    float* out = (float*)d_out;
    unsigned* flags = (unsigned*)d_ws;            // [0, NGROUP) tagged fps indices
    float* partials = (float*)d_ws + NGROUP;      // [NGROUP, NGROUP+NPART)

    LossParams P;
    const double ps[NPCT] = {0.02, 0.04, 0.06, 0.08, 0.10};
    for (int i = 0; i < NPCT; ++i) {
        P.nsample[i] = (int)(NPTS * ps[i]);
        double r = std::sqrt(ps[i] * 1.0);
        P.r2[i] = (float)(r * r);
        double w = (ps[i] * 100.0) * (ps[i] * 100.0);
        P.wscale[i] = (float)(w / (double)(2 * NPOINT * NPCT));
    }
    P.expect_len = (float)std::sqrt(3.14159265358979323846 / (double)NPTS);

    fused_kernel<<<dim3(2 + NPART), dim3(256), 0, stream>>>(pcd, flags, partials, P);
    reduce_kernel<<<dim3(1), dim3(256), 0, stream>>>(partials, out);
}

// Round 10
// 247.272 us; speedup vs baseline: 1.7468x; 1.7468x over previous
//
#include <hip/hip_runtime.h>
#include <cmath>

#define NPTS 4096
#define NPOINT 204   // int(4096 * 0.05)
#define NPCT 5
#define MAXNS 409    // int(4096 * 0.10)
#define NGROUP 408   // B * NPOINT
#define NPART (NGROUP * NPCT)
#define FLAG_TAG 0x5A5A1000u
#define FLAG_STRIDE 32          // one 128 B cache line per flag
#define SPIN_LIMIT 200000       // fail-safe: wrong answer instead of hang

typedef unsigned long long u64;
typedef float f32x2 __attribute__((ext_vector_type(2)));

struct LossParams {
    int   nsample[NPCT];
    float r2[NPCT];
    float wscale[NPCT];   // (p*100)^2 / (B*NPOINT*NPCT)
    float expect_len;
};

// ---------------- DPP wave64 reductions ------------------------------------
template <int CTRL>
__device__ __forceinline__ int dpp_imax(int v) {
    int t = __builtin_amdgcn_update_dpp(0, v, CTRL, 0xf, 0xf, true);
    return v > t ? v : t;
}
template <int CTRL>
__device__ __forceinline__ int dpp_imin(int v) {
    int t = __builtin_amdgcn_update_dpp(0x7fffffff, v, CTRL, 0xf, 0xf, false);
    return v < t ? v : t;
}
__device__ __forceinline__ int wave_max_i(int v) {
    v = dpp_imax<0x111>(v); v = dpp_imax<0x112>(v);
    v = dpp_imax<0x114>(v); v = dpp_imax<0x118>(v);
    v = dpp_imax<0x142>(v); v = dpp_imax<0x143>(v);
    return __builtin_amdgcn_readlane(v, 63);
}
__device__ __forceinline__ int wave_min_i(int v) {
    v = dpp_imin<0x111>(v); v = dpp_imin<0x112>(v);
    v = dpp_imin<0x114>(v); v = dpp_imin<0x118>(v);
    v = dpp_imin<0x142>(v); v = dpp_imin<0x143>(v);
    return __builtin_amdgcn_readlane(v, 63);
}
template <int CTRL>
__device__ __forceinline__ u64 dpp_u64max(u64 v) {
    int lo = (int)(unsigned)v;
    int hi = (int)(unsigned)(v >> 32);
    unsigned slo = (unsigned)__builtin_amdgcn_update_dpp(0, lo, CTRL, 0xf, 0xf, true);
    unsigned shi = (unsigned)__builtin_amdgcn_update_dpp(0, hi, CTRL, 0xf, 0xf, true);
    u64 o = ((u64)shi << 32) | slo;
    return v > o ? v : o;
}

// ---------------------------------------------------------------------------
// Fused kernel. Blocks 0,1: FPS for batch b, publishing each selected index
// as a tagged RELAXED atomic word (payload travels IN the flag -> no
// release/acquire needed; R9's release stores + acquire polls on shared
// cache lines caused 640 MB of coherence traffic and 3.5x regression).
// Each flag sits on its own 128 B line; pollers sleep ~2k cyc between loads.
// Blocks 2..: one (group, pct) each — R5-proven group math verbatim.
// ---------------------------------------------------------------------------
__global__ __launch_bounds__(256) void fused_kernel(const float* __restrict__ pcd,
                                                    unsigned* __restrict__ flags,
                                                    float* __restrict__ partials,
                                                    LossParams P) {
    const int t    = threadIdx.x;
    const int wave = t >> 6, lane = t & 63;

    __shared__ u64    skeys[2][4];
    __shared__ float4 scoord[2][4];
    __shared__ float4 gpts[MAXNS + 8];
    __shared__ int    s_wtot[4];
    __shared__ float  s_part[4];
    __shared__ int    s_qi;

    if (blockIdx.x < 2) {
        // ================= FPS part =================
#pragma clang fp contract(off)
        __builtin_amdgcn_s_setprio(3);     // win issue arbitration vs group waves
        const int b = blockIdx.x;
        const float* base = pcd + (size_t)b * NPTS * 3;
        unsigned* fl = flags + b * NPOINT * FLAG_STRIDE;

        f32x2 X[8], Y[8], Z[8], D[8];
        #pragma unroll
        for (int q = 0; q < 8; ++q) {
            int n0 = (2 * q) * 256 + t;
            int n1 = (2 * q + 1) * 256 + t;
            X[q] = (f32x2){base[3 * n0 + 0], base[3 * n1 + 0]};
            Y[q] = (f32x2){base[3 * n0 + 1], base[3 * n1 + 1]};
            Z[q] = (f32x2){base[3 * n0 + 2], base[3 * n1 + 2]};
            D[q] = (f32x2){1e10f, 1e10f};
        }
        if (t == 0)
            __hip_atomic_store(&fl[0], FLAG_TAG | 0u,
                               __ATOMIC_RELAXED, __HIP_MEMORY_SCOPE_AGENT);
        float cx = base[0], cy = base[1], cz = base[2];   // point 0

        for (int it = 1; it < NPOINT; ++it) {
            f32x2 cxx = (f32x2){cx, cx};
            f32x2 cyy = (f32x2){cy, cy};
            f32x2 czz = (f32x2){cz, cz};
            int bb = -1, bi = 0;
            float bx = 0.0f, by = 0.0f, bz = 0.0f;
            #pragma unroll
            for (int q = 0; q < 8; ++q) {
                f32x2 dx = X[q] - cxx, dy = Y[q] - cyy, dz = Z[q] - czz;
                f32x2 d  = (dx * dx + dy * dy) + dz * dz;
                f32x2 dd = D[q];
                float d0 = fminf(dd.x, d.x);
                float d1 = fminf(dd.y, d.y);
                D[q] = (f32x2){d0, d1};
                int b0 = __float_as_int(d0);   // nonneg: int cmp == float cmp
                int b1 = __float_as_int(d1);
                if (b0 > bb) { bb = b0; bi = (2 * q) * 256 + t;
                               bx = X[q].x; by = Y[q].x; bz = Z[q].x; }
                if (b1 > bb) { bb = b1; bi = (2 * q + 1) * 256 + t;
                               bx = X[q].y; by = Y[q].y; bz = Z[q].y; }
            }
            int wmax = wave_max_i(bb);
            int cand = (bb == wmax) ? bi : 0x7fffffff;
            int widx = wave_min_i(cand);       // smallest index among ties
            if (bb == wmax && bi == widx)      // exactly one thread per wave
                scoord[it & 1][wave] = make_float4(bx, by, bz, 0.0f);
            if (lane == 0)
                skeys[it & 1][wave] =
                    ((u64)(unsigned)wmax << 32) | (unsigned)~(unsigned)widx;
            __syncthreads();
            u64 kv = skeys[it & 1][lane & 3];
            kv = dpp_u64max<0x111>(kv);
            kv = dpp_u64max<0x112>(kv);
            unsigned lo3 = (unsigned)__builtin_amdgcn_readlane((int)(unsigned)kv, 3);
            int last = (int)~lo3;
            float4 wc = scoord[it & 1][(last & 255) >> 6];  // winner wave's coords
            cx = wc.x; cy = wc.y; cz = wc.z;
            if (t == 0)
                __hip_atomic_store(&fl[it * FLAG_STRIDE], FLAG_TAG | (unsigned)last,
                                   __ATOMIC_RELAXED, __HIP_MEMORY_SCOPE_AGENT);
        }
        return;
    }

    // ================= GROUP part (R5 math, verbatim) =================
    const int xid  = blockIdx.x - 2;       // 0 .. NPART-1
    const int pidx = xid % NPCT;
    const int gg   = xid / NPCT;           // 0 .. NGROUP-1
    const int b    = gg & 1;               // alternate batches: backfill matches
    const int m    = gg >> 1;              // fps emission order
    const int   ns = P.nsample[pidx];
    const float r2 = P.r2[pidx];
    const float* base = pcd + (size_t)b * NPTS * 3;

    if (t == 0) {
        unsigned v; int spins = 0;
        unsigned* fp = &flags[(b * NPOINT + m) * FLAG_STRIDE];
        for (;;) {
            v = __hip_atomic_load(fp, __ATOMIC_RELAXED, __HIP_MEMORY_SCOPE_AGENT);
            if ((v & 0xFFFFF000u) == FLAG_TAG) break;
            if (++spins > SPIN_LIMIT) { v = FLAG_TAG; break; }   // no-hang fail-safe
            __builtin_amdgcn_s_sleep(32);    // ~2k cyc between polls
        }
        s_qi = (int)(v & 0xFFFu);
    }
    __syncthreads();
    const int qi = s_qi;
    const float qx = base[3 * qi + 0], qy = base[3 * qi + 1], qz = base[3 * qi + 2];

    // ---- Phase A pass 1: ballot the wave's 16 sub-chunks of 64 points ----
    unsigned long long msk[16];
    int lbase[16];
    int run = 0;
    #pragma unroll 4
    for (int s = 0; s < 16; ++s) {
        int n = wave * 1024 + s * 64 + lane;
        float x = base[3 * n + 0];
        float y = base[3 * n + 1];
        float z = base[3 * n + 2];
        float d2;
        {
#pragma clang fp contract(off)
            float dx = qx - x, dy = qy - y, dz = qz - z;
            float aa = dx * dx, bb = dy * dy, cc = dz * dz;
            d2 = (aa + bb) + cc;
        }
        msk[s] = __ballot(d2 < r2);        // strict <, matches reference
        lbase[s] = run;
        run += __popcll(msk[s]);
    }
    if (lane == 0) s_wtot[wave] = run;
    __syncthreads();
    int w0 = s_wtot[0], w1 = s_wtot[1], w2 = s_wtot[2], w3 = s_wtot[3];
    int Bw = (wave > 0 ? w0 : 0) + (wave > 1 ? w1 : 0) + (wave > 2 ? w2 : 0);
    int cnt  = w0 + w1 + w2 + w3;
    int cntB = cnt < ns ? cnt : ns;        // real points kept
    const int npad = ns - cntB;

    // ---- Phase A pass 2: ordered compaction into LDS, w = |p|^2 ----
    #pragma unroll 4
    for (int s = 0; s < 16; ++s) {
        int gb = Bw + lbase[s];            // wave-uniform
        if (gb >= ns) break;
        unsigned long long mk = msk[s];
        bool in = (mk >> lane) & 1ull;
        int pos = gb + __popcll(mk & ((1ull << lane) - 1ull));
        if (in && pos < ns) {
            int n = wave * 1024 + s * 64 + lane;
            float x = base[3 * n], y = base[3 * n + 1], z = base[3 * n + 2];
            float sq = fmaf(x, x, fmaf(y, y, z * z));
            gpts[pos] = make_float4(x, y, z, sq);
        }
    }
    if (t < 8) gpts[cntB + t] = make_float4(1e6f, 1e6f, 1e6f, 3e12f);  // sentinels
    __syncthreads();

    // ---- Phase B: 2nd-smallest h (incl. self) via med3; d2 = sq_i + m2 ----
    float sum = 0.0f;
    if (cntB > 256) {
        const int i0 = t, i1 = t + 256;
        const bool a1 = i1 < cntB;
        float4 p0 = gpts[i0];
        float4 p1 = gpts[a1 ? i1 : 0];
        float m10 = 1e30f, m20 = 1e30f;
        float m11 = 1e30f, m21 = 1e30f;
        for (int jt = 0; jt < cntB; jt += 8) {
            #pragma unroll
            for (int u = 0; u < 8; ++u) {
                float4 a = gpts[jt + u];
                float tt, h;
                tt = p0.x * a.x; tt = fmaf(p0.y, a.y, tt); tt = fmaf(p0.z, a.z, tt);
                h = fmaf(-2.0f, tt, a.w);
                m20 = __builtin_amdgcn_fmed3f(m10, m20, h);
                m10 = fminf(m10, h);
                tt = p1.x * a.x; tt = fmaf(p1.y, a.y, tt); tt = fmaf(p1.z, a.z, tt);
                h = fmaf(-2.0f, tt, a.w);
                m21 = __builtin_amdgcn_fmed3f(m11, m21, h);
                m11 = fminf(m11, h);
            }
        }
        float d0 = fmaxf(p0.w + m20, 0.0f);
        float d1 = fmaxf(p1.w + m21, 0.0f);
        if (!(i0 == 0 && npad > 0)) sum += sqrtf(d0);
        if (a1) sum += sqrtf(d1);
    } else {
        for (int i = t; i < cntB; i += 256) {
            float4 pi = gpts[i];
            float m1 = 1e30f, m2 = 1e30f;
            for (int jt = 0; jt < cntB; jt += 8) {
                #pragma unroll
                for (int u = 0; u < 8; ++u) {
                    float4 a = gpts[jt + u];
                    float tt, h;
                    tt = pi.x * a.x; tt = fmaf(pi.y, a.y, tt); tt = fmaf(pi.z, a.z, tt);
                    h = fmaf(-2.0f, tt, a.w);
                    m2 = __builtin_amdgcn_fmed3f(m1, m2, h);
                    m1 = fminf(m1, h);
                }
            }
            float dmin = fmaxf(pi.w + m2, 0.0f);
            if (!(i == 0 && npad > 0)) sum += sqrtf(dmin);
        }
    }
    #pragma unroll
    for (int off = 32; off; off >>= 1) sum += __shfl_down(sum, off);
    if (lane == 0) s_part[wave] = sum;
    __syncthreads();
    if (t == 0) {
        float tot = s_part[0] + s_part[1] + s_part[2] + s_part[3] + 0.1f * (float)ns;
        float u  = tot / (float)ns;
        float du = u - P.expect_len;
        partials[xid] = du * du / (P.expect_len + 0.1f) * P.wscale[pidx];
    }
}

// ---------------------------------------------------------------------------
// Reduce: sum the 2040 per-block partials -> d_out (no atomics anywhere).
// ---------------------------------------------------------------------------
__global__ __launch_bounds__(256) void reduce_kernel(const float* __restrict__ partials,
                                                     float* __restrict__ out) {
    const int t = threadIdx.x;
    __shared__ float sp[4];
    float s = 0.0f;
    for (int i = t; i < NPART; i += 256) s += partials[i];
    #pragma unroll
    for (int off = 32; off; off >>= 1) s += __shfl_down(s, off);
    if ((t & 63) == 0) sp[t >> 6] = s;
    __syncthreads();
    if (t == 0) out[0] = sp[0] + sp[1] + sp[2] + sp[3];
}

extern "C" void kernel_launch(void* const* d_in, const int* in_sizes, int n_in,
                              void* d_out, int out_size, void* d_ws, size_t ws_size,
                              hipStream_t stream) {
    const float* pcd = (const float*)d_in[0];
    float* out = (float*)d_out;
    unsigned* flags = (unsigned*)d_ws;                       // NGROUP lines (52 KB)
    float* partials = (float*)d_ws + NGROUP * FLAG_STRIDE;   // NPART floats

    LossParams P;
    const double ps[NPCT] = {0.02, 0.04, 0.06, 0.08, 0.10};
    for (int i = 0; i < NPCT; ++i) {
        P.nsample[i] = (int)(NPTS * ps[i]);
        double r = std::sqrt(ps[i] * 1.0);
        P.r2[i] = (float)(r * r);
        double w = (ps[i] * 100.0) * (ps[i] * 100.0);
        P.wscale[i] = (float)(w / (double)(2 * NPOINT * NPCT));
    }
    P.expect_len = (float)std::sqrt(3.14159265358979323846 / (double)NPTS);

    fused_kernel<<<dim3(2 + NPART), dim3(256), 0, stream>>>(pcd, flags, partials, P);
    reduce_kernel<<<dim3(1), dim3(256), 0, stream>>>(partials, out);
}